// Round 11
// baseline (1087.368 us; speedup 1.0000x reference)
//
#include <hip/hip_runtime.h>
#include <cstdint>

// ---------------------------------------------------------------------------
// DiffusionLayer: 3x GATv2 (rate: user->item, ratedby: item->user,
// trust: user->user) + attention-gated fusion. All f32, D = 64.
//
// R10 (resubmitted R11; R10 bench hit GPUAcquisitionTimeout):
//      CSR build de-latency-ified. R9 profile: scatter3 250us (24%) at
//      0.9% VALU / 11% HBM / 81% occ -> latency-bound on random-address
//      device-scope atomics (return value gates the esrc store).
//      Now 8 edges/thread (int4 x2 loads, 8 atomics in flight), and
//      copy_ptr fused into finalize_ptr via atomicSub-from-row-end
//      (endp[] aliases cnt; rows fill back-to-front, order-irrelevant).
// R9 = R5 changeset (gat_row 4x16-lane groups, batched CSR, float4 proj64).
// ---------------------------------------------------------------------------

#define D 64
#define FH_BLOCKS 1024

__device__ __forceinline__ float waveReduceSum(float v) {
#pragma unroll
  for (int off = 32; off > 0; off >>= 1) v += __shfl_xor(v, off, 64);
  return v;
}

__device__ __forceinline__ void fma4(float4& a, float s, const float4& b) {
  a.x += s * b.x;
  a.y += s * b.y;
  a.z += s * b.z;
  a.w += s * b.w;
}

// ---- projection: Y = X @ W + b;  X[N,64], W[64,64] row-major, b[64] -------
__global__ __launch_bounds__(256) void proj64_kernel(
    const float* __restrict__ X, const float* __restrict__ W,
    const float* __restrict__ b, float* __restrict__ Y, int N) {
  __shared__ __align__(16) float Ws[64 * 64];
  __shared__ __align__(16) float Xs[64][68];  // row stride 272B (17x16B)
  const int t = threadIdx.x;
  const int row0 = blockIdx.x * 64;

#pragma unroll
  for (int i = 0; i < 16; ++i) Ws[t + i * 256] = W[t + i * 256];
#pragma unroll
  for (int i = 0; i < 16; ++i) {
    int idx = t + i * 256;  // 0..4095
    int r = idx >> 6, k = idx & 63;
    int gr = row0 + r;
    Xs[r][k] = (gr < N) ? X[gr * 64 + k] : 0.f;
  }
  __syncthreads();

  const int jt = (t & 15) * 4;  // column group (4 cols)
  const int rt = (t >> 4) * 4;  // row group (4 rows)
  float4 a0 = *reinterpret_cast<const float4*>(b + jt);
  float4 a1 = a0, a2 = a0, a3 = a0;

#pragma unroll 4
  for (int k4 = 0; k4 < 16; ++k4) {
    float4 w0 = *reinterpret_cast<const float4*>(&Ws[(k4 * 4 + 0) * 64 + jt]);
    float4 w1 = *reinterpret_cast<const float4*>(&Ws[(k4 * 4 + 1) * 64 + jt]);
    float4 w2 = *reinterpret_cast<const float4*>(&Ws[(k4 * 4 + 2) * 64 + jt]);
    float4 w3 = *reinterpret_cast<const float4*>(&Ws[(k4 * 4 + 3) * 64 + jt]);
    float4 x0 = *reinterpret_cast<const float4*>(&Xs[rt + 0][k4 * 4]);
    float4 x1 = *reinterpret_cast<const float4*>(&Xs[rt + 1][k4 * 4]);
    float4 x2 = *reinterpret_cast<const float4*>(&Xs[rt + 2][k4 * 4]);
    float4 x3 = *reinterpret_cast<const float4*>(&Xs[rt + 3][k4 * 4]);
    fma4(a0, x0.x, w0); fma4(a0, x0.y, w1); fma4(a0, x0.z, w2); fma4(a0, x0.w, w3);
    fma4(a1, x1.x, w0); fma4(a1, x1.y, w1); fma4(a1, x1.z, w2); fma4(a1, x1.w, w3);
    fma4(a2, x2.x, w0); fma4(a2, x2.y, w1); fma4(a2, x2.z, w2); fma4(a2, x2.w, w3);
    fma4(a3, x3.x, w0); fma4(a3, x3.y, w1); fma4(a3, x3.z, w2); fma4(a3, x3.w, w3);
  }

  int gr = row0 + rt;
  if (gr + 0 < N) *reinterpret_cast<float4*>(&Y[(gr + 0) * 64 + jt]) = a0;
  if (gr + 1 < N) *reinterpret_cast<float4*>(&Y[(gr + 1) * 64 + jt]) = a1;
  if (gr + 2 < N) *reinterpret_cast<float4*>(&Y[(gr + 2) * 64 + jt]) = a2;
  if (gr + 3 < N) *reinterpret_cast<float4*>(&Y[(gr + 3) * 64 + jt]) = a3;
}

// ================== batched CSR construction (3 relations) =================
// Row space: trust rows [0,NU), ratedby rows [NU,2NU), rate rows [2NU,2NU+NI).
// Edge space: trust [0,E), ratedby [E,2E), rate [2E,3E).

// fast path: 8 edges/thread, requires E % 8 == 0 (one-shot grid, no stride)
__global__ __launch_bounds__(256) void hist3_v8_kernel(
    const int* __restrict__ d0, const int* __restrict__ d1,
    const int* __restrict__ d2, int b1, int b2, int* __restrict__ counts,
    int E) {
  int i = (blockIdx.x * 256 + threadIdx.x) * 8;
  if (i >= 3 * E) return;
  int r = (i >= 2 * E) ? 2 : (i >= E) ? 1 : 0;
  const int* dp = (r == 0) ? d0 : (r == 1) ? d1 : d2;
  int base = (r == 0) ? 0 : (r == 1) ? b1 : b2;
  int j = i - r * E;
  int4 da = *reinterpret_cast<const int4*>(dp + j);
  int4 db = *reinterpret_cast<const int4*>(dp + j + 4);
  atomicAdd(&counts[da.x + base], 1);
  atomicAdd(&counts[da.y + base], 1);
  atomicAdd(&counts[da.z + base], 1);
  atomicAdd(&counts[da.w + base], 1);
  atomicAdd(&counts[db.x + base], 1);
  atomicAdd(&counts[db.y + base], 1);
  atomicAdd(&counts[db.z + base], 1);
  atomicAdd(&counts[db.w + base], 1);
}

// scalar fallback (E % 8 != 0)
__global__ __launch_bounds__(256) void hist3_kernel(
    const int* __restrict__ d0, const int* __restrict__ d1,
    const int* __restrict__ d2, int b1, int b2, int* __restrict__ counts,
    int E) {
  int stride = gridDim.x * 256;
  for (int i = blockIdx.x * 256 + threadIdx.x; i < 3 * E; i += stride) {
    int r = (i >= 2 * E) ? 2 : (i >= E ? 1 : 0);
    int j = i - r * E;
    const int* dp = (r == 0) ? d0 : (r == 1) ? d1 : d2;
    int base = (r == 0) ? 0 : (r == 1) ? b1 : b2;
    atomicAdd(&counts[dp[j] + base], 1);
  }
}

// per-chunk (1024) inclusive scan; incl may alias counts
__global__ __launch_bounds__(1024) void scan_chunk_kernel(
    const int* __restrict__ counts, int* __restrict__ incl,
    int* __restrict__ chunk_tot, int N) {
  __shared__ int sh[1024];
  int t = threadIdx.x;
  int i = blockIdx.x * 1024 + t;
  int x = (i < N) ? counts[i] : 0;
  sh[t] = x;
  __syncthreads();
#pragma unroll
  for (int off = 1; off < 1024; off <<= 1) {
    int v = (t >= off) ? sh[t - off] : 0;
    __syncthreads();
    sh[t] += v;
    __syncthreads();
  }
  if (i < N) incl[i] = sh[t];
  if (t == 1023) chunk_tot[blockIdx.x] = sh[t];
}

__global__ __launch_bounds__(1024) void scan_tops_kernel(
    const int* __restrict__ chunk_tot, int* __restrict__ chunk_off,
    int nchunks) {
  __shared__ int sh[1024];
  int t = threadIdx.x;
  int x = (t < nchunks) ? chunk_tot[t] : 0;
  sh[t] = x;
  __syncthreads();
#pragma unroll
  for (int off = 1; off < 1024; off <<= 1) {
    int v = (t >= off) ? sh[t - off] : 0;
    __syncthreads();
    sh[t] += v;
    __syncthreads();
  }
  if (t < nchunks) chunk_off[t] = sh[t] - x;  // exclusive
}

// row_ptr[i+1] = endp[i] = global inclusive scan. endp may alias incl:
// each thread reads incl[i] before writing endp[i] (same address, same thread).
__global__ __launch_bounds__(256) void finalize_ptr_kernel(
    const int* __restrict__ incl, const int* __restrict__ chunk_off,
    int* __restrict__ row_ptr, int* __restrict__ endp, int N) {
  int i = blockIdx.x * 256 + threadIdx.x;
  if (i >= N) return;
  int v = incl[i] + chunk_off[i >> 10];
  row_ptr[i + 1] = v;
  endp[i] = v;
  if (i == 0) row_ptr[0] = 0;
}

// fast path: 8 edges/thread; positions claimed from row END via atomicSub
// (after completion endp[d] == row_ptr[d]; row fill order is irrelevant).
__global__ __launch_bounds__(256) void scatter3_v8_kernel(
    const int* __restrict__ s0, const int* __restrict__ d0,
    const int* __restrict__ s1, const int* __restrict__ d1,
    const int* __restrict__ s2, const int* __restrict__ d2, int b1, int b2,
    int* __restrict__ endp, int* __restrict__ esrc, int E) {
  int i = (blockIdx.x * 256 + threadIdx.x) * 8;
  if (i >= 3 * E) return;
  int r = (i >= 2 * E) ? 2 : (i >= E) ? 1 : 0;
  const int* dp = (r == 0) ? d0 : (r == 1) ? d1 : d2;
  const int* sp = (r == 0) ? s0 : (r == 1) ? s1 : s2;
  int base = (r == 0) ? 0 : (r == 1) ? b1 : b2;
  int j = i - r * E;
  int4 da = *reinterpret_cast<const int4*>(dp + j);
  int4 db = *reinterpret_cast<const int4*>(dp + j + 4);
  int4 sa = *reinterpret_cast<const int4*>(sp + j);
  int4 sb = *reinterpret_cast<const int4*>(sp + j + 4);
  int p0 = atomicSub(&endp[da.x + base], 1) - 1;
  int p1 = atomicSub(&endp[da.y + base], 1) - 1;
  int p2 = atomicSub(&endp[da.z + base], 1) - 1;
  int p3 = atomicSub(&endp[da.w + base], 1) - 1;
  int p4 = atomicSub(&endp[db.x + base], 1) - 1;
  int p5 = atomicSub(&endp[db.y + base], 1) - 1;
  int p6 = atomicSub(&endp[db.z + base], 1) - 1;
  int p7 = atomicSub(&endp[db.w + base], 1) - 1;
  esrc[p0] = sa.x;
  esrc[p1] = sa.y;
  esrc[p2] = sa.z;
  esrc[p3] = sa.w;
  esrc[p4] = sb.x;
  esrc[p5] = sb.y;
  esrc[p6] = sb.z;
  esrc[p7] = sb.w;
}

// scalar fallback (E % 8 != 0)
__global__ __launch_bounds__(256) void scatter3_kernel(
    const int* __restrict__ s0, const int* __restrict__ d0,
    const int* __restrict__ s1, const int* __restrict__ d1,
    const int* __restrict__ s2, const int* __restrict__ d2, int b1, int b2,
    int* __restrict__ endp, int* __restrict__ esrc, int E) {
  int stride = gridDim.x * 256;
  for (int i = blockIdx.x * 256 + threadIdx.x; i < 3 * E; i += stride) {
    int r = (i >= 2 * E) ? 2 : (i >= E ? 1 : 0);
    int j = i - r * E;
    const int* dp = (r == 0) ? d0 : (r == 1) ? d1 : d2;
    const int* sp = (r == 0) ? s0 : (r == 1) ? s1 : s2;
    int base = (r == 0) ? 0 : (r == 1) ? b1 : b2;
    int pos = atomicSub(&endp[dp[j] + base], 1) - 1;
    esrc[pos] = sp[j];
  }
}

// ================= fused pull-based GATv2 row kernel =======================
// One wave per dst row; 4 groups of 16 lanes, each group owns edges
// j = jbeg+g, +4, ... with float4 channels per lane (4 gathers in flight).
// Per-group online softmax (m,z,acc); groups merged by xor-16/32 butterfly.
__global__ __launch_bounds__(256) void gat_row_kernel(
    const float* __restrict__ fs, const float* __restrict__ fd,
    const int* __restrict__ row_ptr, const int* __restrict__ esrc,
    const float* __restrict__ attn, const float* __restrict__ bias,
    const float* __restrict__ resid, float* __restrict__ out, int Nd) {
  const int lane = threadIdx.x & 63;
  const int d = (blockIdx.x * 256 + threadIdx.x) >> 6;
  if (d >= Nd) return;
  const int g = lane >> 4;        // group 0..3
  const int c = (lane & 15) * 4;  // channel base

  const float4 aw = *reinterpret_cast<const float4*>(&attn[c]);
  const float4 fdv = *reinterpret_cast<const float4*>(&fd[d * 64 + c]);
  const int jbeg = row_ptr[d];
  const int jend = row_ptr[d + 1];

  float m = -1e30f, z = 0.f;
  float4 acc = {0.f, 0.f, 0.f, 0.f};
  for (int j = jbeg + g; j < jend; j += 4) {
    int s = esrc[j];
    float4 fsv = *reinterpret_cast<const float4*>(&fs[s * 64 + c]);
    float vx = fsv.x + fdv.x; vx = (vx > 0.f) ? vx : 0.2f * vx;
    float vy = fsv.y + fdv.y; vy = (vy > 0.f) ? vy : 0.2f * vy;
    float vz = fsv.z + fdv.z; vz = (vz > 0.f) ? vz : 0.2f * vz;
    float vw = fsv.w + fdv.w; vw = (vw > 0.f) ? vw : 0.2f * vw;
    float p = vx * aw.x + vy * aw.y + vz * aw.z + vw * aw.w;
#pragma unroll
    for (int off = 1; off < 16; off <<= 1) p += __shfl_xor(p, off, 64);
    float mn = fmaxf(m, p);
    float sc = __expf(m - mn);  // first edge: exp(-1e30-p) -> 0
    float w = __expf(p - mn);
    z = z * sc + w;
    acc.x = acc.x * sc + w * fsv.x;
    acc.y = acc.y * sc + w * fsv.y;
    acc.z = acc.z * sc + w * fsv.z;
    acc.w = acc.w * sc + w * fsv.w;
    m = mn;
  }
  // merge the 4 groups (empty groups have m=-1e30, z=0 -> contribute 0)
#pragma unroll
  for (int off = 16; off < 64; off <<= 1) {
    float m_o = __shfl_xor(m, off, 64);
    float z_o = __shfl_xor(z, off, 64);
    float ax = __shfl_xor(acc.x, off, 64);
    float ay = __shfl_xor(acc.y, off, 64);
    float az = __shfl_xor(acc.z, off, 64);
    float aww = __shfl_xor(acc.w, off, 64);
    float mn = fmaxf(m, m_o);
    float s0 = __expf(m - mn), s1 = __expf(m_o - mn);
    z = z * s0 + z_o * s1;
    acc.x = acc.x * s0 + ax * s1;
    acc.y = acc.y * s0 + ay * s1;
    acc.z = acc.z * s0 + az * s1;
    acc.w = acc.w * s0 + aww * s1;
    m = mn;
  }
  if (g == 0) {
    float inv = (z > 0.f) ? 1.f / z : 0.f;
    float4 bb = *reinterpret_cast<const float4*>(&bias[c]);
    float4 o;
    o.x = acc.x * inv + bb.x;
    o.y = acc.y * inv + bb.y;
    o.z = acc.z * inv + bb.z;
    o.w = acc.w * inv + bb.w;
    if (resid) {
      float4 rr = *reinterpret_cast<const float4*>(&resid[d * 64 + c]);
      o.x += rr.x; o.y += rr.y; o.z += rr.z; o.w += rr.w;
    }
    *reinterpret_cast<float4*>(&out[d * 64 + c]) = o;
  }
}

// ---- collapse Linear(128,128)->Linear(128,1) into one 128-vector ----------
// wbuf layout: [0..127]=w_inf, [128]=c_inf, [130..257]=w_int, [258]=c_int
__global__ __launch_bounds__(256) void weff_kernel(
    const float* __restrict__ W1i, const float* __restrict__ b1i,
    const float* __restrict__ W2i, const float* __restrict__ b2i,
    const float* __restrict__ W1t, const float* __restrict__ b1t,
    const float* __restrict__ W2t, const float* __restrict__ b2t,
    float* __restrict__ wbuf) {
  int t = threadIdx.x;
  const float* W1 = (t < 128) ? W1i : W1t;
  const float* W2 = (t < 128) ? W2i : W2t;
  int i = t & 127;
  int base = (t < 128) ? 0 : 130;
  float s = 0.f;
  for (int j = 0; j < 128; ++j) s += W1[i * 128 + j] * W2[j];
  wbuf[base + i] = s;
  if (i == 0) {
    const float* b1 = (t < 128) ? b1i : b1t;
    const float* b2 = (t < 128) ? b2i : b2t;
    float c = b2[0];
    for (int j = 0; j < 128; ++j) c += b1[j] * W2[j];
    wbuf[base + 128] = c;
  }
}

// ---- h_inf/h_int per user + per-block BN partial sums (NO atomics) --------
__global__ __launch_bounds__(256) void fuse_h_kernel(
    const float* __restrict__ ue, const float* __restrict__ p,
    const float* __restrict__ q, const float* __restrict__ wbuf,
    float* __restrict__ h_inf, float* __restrict__ h_int,
    double* __restrict__ partials, int NU) {
  const int lane = threadIdx.x & 63;
  const int wv = threadIdx.x >> 6;
  const int wave = blockIdx.x * 4 + wv;
  const int nwaves = gridDim.x * 4;

  const float wi_u = wbuf[lane];
  const float wi_p = wbuf[64 + lane];
  const float wt_u = wbuf[130 + lane];
  const float wt_q = wbuf[194 + lane];
  const float ci = wbuf[128];
  const float ct = wbuf[258];

  double s0 = 0., s1 = 0., s2 = 0., s3 = 0.;
  for (int u = wave; u < NU; u += nwaves) {
    float uv = ue[u * 64 + lane];
    float hi = uv * wi_u + p[u * 64 + lane] * wi_p;
    float ht = uv * wt_u + q[u * 64 + lane] * wt_q;
    hi = waveReduceSum(hi) + ci;
    ht = waveReduceSum(ht) + ct;
    if (lane == 0) {
      h_inf[u] = hi;
      h_int[u] = ht;
    }
    s0 += (double)hi;
    s1 += (double)hi * (double)hi;
    s2 += (double)ht;
    s3 += (double)ht * (double)ht;
  }

  __shared__ double sh[4][4];
  if (lane == 0) {
    sh[wv][0] = s0;
    sh[wv][1] = s1;
    sh[wv][2] = s2;
    sh[wv][3] = s3;
  }
  __syncthreads();
  if (threadIdx.x < 4) {
    int k = threadIdx.x;
    partials[blockIdx.x * 4 + k] = sh[0][k] + sh[1][k] + sh[2][k] + sh[3][k];
  }
}

__global__ __launch_bounds__(256) void reduce_stats_kernel(
    const double* __restrict__ partials, double* __restrict__ stats,
    int nblocks) {
  int k = threadIdx.x & 3;
  int bstart = threadIdx.x >> 2;  // 0..63
  double s = 0.;
  for (int b = bstart; b < nblocks; b += 64) s += partials[b * 4 + k];
  __shared__ double sh[256];
  sh[threadIdx.x] = s;
  __syncthreads();
  if (threadIdx.x < 4) {
    double acc = 0.;
    for (int i = 0; i < 64; ++i) acc += sh[i * 4 + threadIdx.x];
    stats[threadIdx.x] = acc;
  }
}

// ---- final: BN + leaky + 2-way softmax + gated sum + residual -------------
__global__ __launch_bounds__(256) void fuse_out_kernel(
    const float* __restrict__ ue, const float* __restrict__ p,
    const float* __restrict__ q, const float* __restrict__ h_inf,
    const float* __restrict__ h_int, const double* __restrict__ stats,
    const float* __restrict__ gi, const float* __restrict__ bei,
    const float* __restrict__ gt, const float* __restrict__ bet,
    float* __restrict__ out, int NU) {
  int i = blockIdx.x * 256 + threadIdx.x;
  if (i >= NU * 64) return;
  int u = i >> 6;
  double invN = 1.0 / (double)NU;
  float mu_i = (float)(stats[0] * invN);
  float var_i = (float)(stats[1] * invN) - mu_i * mu_i;
  float mu_t = (float)(stats[2] * invN);
  float var_t = (float)(stats[3] * invN) - mu_t * mu_t;
  float si = gi[0] * (h_inf[u] - mu_i) / sqrtf(var_i + 1e-5f) + bei[0];
  si = (si > 0.f) ? si : 0.01f * si;
  float st = gt[0] * (h_int[u] - mu_t) / sqrtf(var_t + 1e-5f) + bet[0];
  st = (st > 0.f) ? st : 0.01f * st;
  float mx = fmaxf(si, st);
  float e0 = expf(si - mx), e1 = expf(st - mx);
  float inv = 1.f / (e0 + e1);
  out[i] = (e0 * inv) * p[i] + (e1 * inv) * q[i] + ue[i];
}

// ---------------------------------------------------------------------------
extern "C" void kernel_launch(void* const* d_in, const int* in_sizes, int n_in,
                              void* d_out, int out_size, void* d_ws,
                              size_t ws_size, hipStream_t stream) {
  const float* user_emb = (const float*)d_in[0];
  const float* item_emb = (const float*)d_in[1];
  const int* rate_src = (const int*)d_in[2];
  const int* rate_dst = (const int*)d_in[3];
  const int* rb_src = (const int*)d_in[4];
  const int* rb_dst = (const int*)d_in[5];
  const int* tr_src = (const int*)d_in[6];
  const int* tr_dst = (const int*)d_in[7];
  const float* rate_Wsrc = (const float*)d_in[8];
  const float* rate_bsrc = (const float*)d_in[9];
  const float* rate_Wdst = (const float*)d_in[10];
  const float* rate_bdst = (const float*)d_in[11];
  const float* rate_attn = (const float*)d_in[12];
  const float* rate_bias = (const float*)d_in[13];
  const float* rb_Wsrc = (const float*)d_in[14];
  const float* rb_bsrc = (const float*)d_in[15];
  const float* rb_Wdst = (const float*)d_in[16];
  const float* rb_bdst = (const float*)d_in[17];
  const float* rb_attn = (const float*)d_in[18];
  const float* rb_bias = (const float*)d_in[19];
  const float* tr_Wsrc = (const float*)d_in[20];
  const float* tr_bsrc = (const float*)d_in[21];
  const float* tr_Wdst = (const float*)d_in[22];
  const float* tr_bdst = (const float*)d_in[23];
  const float* tr_attn = (const float*)d_in[24];
  const float* tr_bias = (const float*)d_in[25];
  const float* inf_W1 = (const float*)d_in[26];
  const float* inf_b1 = (const float*)d_in[27];
  const float* inf_W2 = (const float*)d_in[28];
  const float* inf_b2 = (const float*)d_in[29];
  const float* inf_g = (const float*)d_in[30];
  const float* inf_be = (const float*)d_in[31];
  const float* int_W1 = (const float*)d_in[32];
  const float* int_b1 = (const float*)d_in[33];
  const float* int_W2 = (const float*)d_in[34];
  const float* int_b2 = (const float*)d_in[35];
  const float* int_g = (const float*)d_in[36];
  const float* int_be = (const float*)d_in[37];

  const int NU = in_sizes[0] / 64;
  const int NI = in_sizes[1] / 64;
  const int E = in_sizes[2];
  const size_t MX = (size_t)((NU > NI) ? NU : NI);
  const int NT = 2 * NU + NI;  // concatenated row space

  // workspace carve-up (256B aligned)
  char* ws = (char*)d_ws;
  size_t off = 0;
  auto alloc = [&](size_t bytes) -> void* {
    void* pp = ws + off;
    off += (bytes + 255) & ~(size_t)255;
    return pp;
  };
  float* fs = (float*)alloc(MX * 64 * 4);
  float* fd = (float*)alloc(MX * 64 * 4);
  float* q_acc = (float*)alloc((size_t)NU * 64 * 4);
  int* cnt = (int*)alloc((size_t)NT * 4);  // counts -> incl scan -> endp
  int* row_ptr = (int*)alloc(((size_t)NT + 1) * 4);
  int* esrc = (int*)alloc((size_t)3 * E * 4);
  int* chunk_tot = (int*)alloc(1024 * 4);
  int* chunk_off = (int*)alloc(1024 * 4);
  float* h_inf = (float*)alloc((size_t)NU * 4);
  float* h_int = (float*)alloc((size_t)NU * 4);
  float* wbuf = (float*)alloc(272 * 4);
  double* stats = (double*)alloc(4 * 8);
  double* partials = (double*)alloc((size_t)FH_BLOCKS * 4 * 8);

  float* p_acc = (float*)d_out;                       // user region of output
  float* item_acc = (float*)d_out + (size_t)NU * 64;  // item region

  auto projGrid = [](int n) { return (n + 63) / 64; };
  auto elemGrid = [](int total) { return (total + 255) / 256; };

  weff_kernel<<<1, 256, 0, stream>>>(inf_W1, inf_b1, inf_W2, inf_b2, int_W1,
                                     int_b1, int_W2, int_b2, wbuf);

  // ---- batched CSR build over all 3 relations ----
  hipMemsetAsync(cnt, 0, (size_t)NT * 4, stream);
  if ((E & 7) == 0) {
    int blocks8 = (3 * E / 8 + 255) / 256;
    hist3_v8_kernel<<<blocks8, 256, 0, stream>>>(tr_dst, rb_dst, rate_dst, NU,
                                                 2 * NU, cnt, E);
  } else {
    hist3_kernel<<<2048, 256, 0, stream>>>(tr_dst, rb_dst, rate_dst, NU,
                                           2 * NU, cnt, E);
  }
  int nchunks = (NT + 1023) / 1024;
  scan_chunk_kernel<<<nchunks, 1024, 0, stream>>>(cnt, cnt, chunk_tot, NT);
  scan_tops_kernel<<<1, 1024, 0, stream>>>(chunk_tot, chunk_off, nchunks);
  finalize_ptr_kernel<<<elemGrid(NT), 256, 0, stream>>>(cnt, chunk_off,
                                                        row_ptr, cnt, NT);
  if ((E & 7) == 0) {
    int blocks8 = (3 * E / 8 + 255) / 256;
    scatter3_v8_kernel<<<blocks8, 256, 0, stream>>>(
        tr_src, tr_dst, rb_src, rb_dst, rate_src, rate_dst, NU, 2 * NU, cnt,
        esrc, E);
  } else {
    scatter3_kernel<<<2048, 256, 0, stream>>>(tr_src, tr_dst, rb_src, rb_dst,
                                              rate_src, rate_dst, NU, 2 * NU,
                                              cnt, esrc, E);
  }

  // ---- trust: user -> user  => p_hair (d_out user region) ----
  proj64_kernel<<<projGrid(NU), 256, 0, stream>>>(user_emb, tr_Wsrc, tr_bsrc,
                                                  fs, NU);
  proj64_kernel<<<projGrid(NU), 256, 0, stream>>>(user_emb, tr_Wdst, tr_bdst,
                                                  fd, NU);
  gat_row_kernel<<<(NU + 3) / 4, 256, 0, stream>>>(
      fs, fd, row_ptr, esrc, tr_attn, tr_bias, nullptr, p_acc, NU);

  // ---- ratedby: item -> user  => q_hair ----
  proj64_kernel<<<projGrid(NI), 256, 0, stream>>>(item_emb, rb_Wsrc, rb_bsrc,
                                                  fs, NI);
  proj64_kernel<<<projGrid(NU), 256, 0, stream>>>(user_emb, rb_Wdst, rb_bdst,
                                                  fd, NU);
  gat_row_kernel<<<(NU + 3) / 4, 256, 0, stream>>>(
      fs, fd, row_ptr + NU, esrc, rb_attn, rb_bias, nullptr, q_acc, NU);

  // ---- rate: user -> item  => item_out (d_out item region, +resid) ----
  proj64_kernel<<<projGrid(NU), 256, 0, stream>>>(user_emb, rate_Wsrc,
                                                  rate_bsrc, fs, NU);
  proj64_kernel<<<projGrid(NI), 256, 0, stream>>>(item_emb, rate_Wdst,
                                                  rate_bdst, fd, NI);
  gat_row_kernel<<<(NI + 3) / 4, 256, 0, stream>>>(
      fs, fd, row_ptr + 2 * NU, esrc, rate_attn, rate_bias, item_emb,
      item_acc, NI);

  // ---- fusion ----
  fuse_h_kernel<<<FH_BLOCKS, 256, 0, stream>>>(user_emb, p_acc, q_acc, wbuf,
                                               h_inf, h_int, partials, NU);
  reduce_stats_kernel<<<1, 256, 0, stream>>>(partials, stats, FH_BLOCKS);
  fuse_out_kernel<<<elemGrid(NU * 64), 256, 0, stream>>>(
      user_emb, p_acc, q_acc, h_inf, h_int, stats, inf_g, inf_be, int_g,
      int_be, (float*)d_out, NU);
}

// Round 12
// 954.799 us; speedup vs baseline: 1.1388x; 1.1388x over previous
//
#include <hip/hip_runtime.h>
#include <cstdint>

// ---------------------------------------------------------------------------
// DiffusionLayer: 3x GATv2 (rate: user->item, ratedby: item->user,
// trust: user->user) + attention-gated fusion. All f32, D = 64.
//
// R12: CSR build rewritten as two-level LDS-localized binning.
//      R11 disproved the latency theory: 8 atomics/thread in flight changed
//      nothing (250->236us) -> scatter is THROUGHPUT-bound on random
//      device-scope atomics + 16x partial-line write amplification
//      (WRITE_SIZE 209MB for a 12MB array). Fix: confine ALL random access
//      to LDS. bin_count/bin_scan/bin_scatter group edges by 4096-row
//      bucket (LDS hist + LDS cursors, bucket-grouped writes -> full-dirty
//      lines); row_count builds per-row counts in LDS per bucket (coalesced
//      global writes, replaces hist3); bucket_scatter places edges via LDS
//      row-cursors into the bucket's L2-resident esrc slice.
//      Pair buffers (24MB) alias fs/fd (only used after CSR build).
// R9/R5 lineage: gat_row 4x16-lane groups, float4 proj64, fused epilogues.
// ---------------------------------------------------------------------------

#define D 64
#define FH_BLOCKS 1024
#define RPB 4096      // rows per bucket
#define RPB_SHIFT 12
#define NCH 256       // edge chunks for binning (== blockDim of bin kernels)

__device__ __forceinline__ float waveReduceSum(float v) {
#pragma unroll
  for (int off = 32; off > 0; off >>= 1) v += __shfl_xor(v, off, 64);
  return v;
}

__device__ __forceinline__ void fma4(float4& a, float s, const float4& b) {
  a.x += s * b.x;
  a.y += s * b.y;
  a.z += s * b.z;
  a.w += s * b.w;
}

// ---- projection: Y = X @ W + b;  X[N,64], W[64,64] row-major, b[64] -------
__global__ __launch_bounds__(256) void proj64_kernel(
    const float* __restrict__ X, const float* __restrict__ W,
    const float* __restrict__ b, float* __restrict__ Y, int N) {
  __shared__ __align__(16) float Ws[64 * 64];
  __shared__ __align__(16) float Xs[64][68];  // row stride 272B (17x16B)
  const int t = threadIdx.x;
  const int row0 = blockIdx.x * 64;

#pragma unroll
  for (int i = 0; i < 16; ++i) Ws[t + i * 256] = W[t + i * 256];
#pragma unroll
  for (int i = 0; i < 16; ++i) {
    int idx = t + i * 256;  // 0..4095
    int r = idx >> 6, k = idx & 63;
    int gr = row0 + r;
    Xs[r][k] = (gr < N) ? X[gr * 64 + k] : 0.f;
  }
  __syncthreads();

  const int jt = (t & 15) * 4;  // column group (4 cols)
  const int rt = (t >> 4) * 4;  // row group (4 rows)
  float4 a0 = *reinterpret_cast<const float4*>(b + jt);
  float4 a1 = a0, a2 = a0, a3 = a0;

#pragma unroll 4
  for (int k4 = 0; k4 < 16; ++k4) {
    float4 w0 = *reinterpret_cast<const float4*>(&Ws[(k4 * 4 + 0) * 64 + jt]);
    float4 w1 = *reinterpret_cast<const float4*>(&Ws[(k4 * 4 + 1) * 64 + jt]);
    float4 w2 = *reinterpret_cast<const float4*>(&Ws[(k4 * 4 + 2) * 64 + jt]);
    float4 w3 = *reinterpret_cast<const float4*>(&Ws[(k4 * 4 + 3) * 64 + jt]);
    float4 x0 = *reinterpret_cast<const float4*>(&Xs[rt + 0][k4 * 4]);
    float4 x1 = *reinterpret_cast<const float4*>(&Xs[rt + 1][k4 * 4]);
    float4 x2 = *reinterpret_cast<const float4*>(&Xs[rt + 2][k4 * 4]);
    float4 x3 = *reinterpret_cast<const float4*>(&Xs[rt + 3][k4 * 4]);
    fma4(a0, x0.x, w0); fma4(a0, x0.y, w1); fma4(a0, x0.z, w2); fma4(a0, x0.w, w3);
    fma4(a1, x1.x, w0); fma4(a1, x1.y, w1); fma4(a1, x1.z, w2); fma4(a1, x1.w, w3);
    fma4(a2, x2.x, w0); fma4(a2, x2.y, w1); fma4(a2, x2.z, w2); fma4(a2, x2.w, w3);
    fma4(a3, x3.x, w0); fma4(a3, x3.y, w1); fma4(a3, x3.z, w2); fma4(a3, x3.w, w3);
  }

  int gr = row0 + rt;
  if (gr + 0 < N) *reinterpret_cast<float4*>(&Y[(gr + 0) * 64 + jt]) = a0;
  if (gr + 1 < N) *reinterpret_cast<float4*>(&Y[(gr + 1) * 64 + jt]) = a1;
  if (gr + 2 < N) *reinterpret_cast<float4*>(&Y[(gr + 2) * 64 + jt]) = a2;
  if (gr + 3 < N) *reinterpret_cast<float4*>(&Y[(gr + 3) * 64 + jt]) = a3;
}

// ============ two-level binned CSR construction (3 relations) ==============
// Row space: trust rows [0,NU), ratedby rows [NU,2NU), rate rows [2NU,2NU+NI).
// Edge space: trust [0,E), ratedby [E,2E), rate [2E,3E).
// Bucket b = rows [b*RPB, (b+1)*RPB). NB = ceil(NT/RPB) must be <= 256.

// per-chunk LDS histogram over buckets -> chunk_hist[bucket*NCH + chunk]
__global__ __launch_bounds__(256) void bin_count_kernel(
    const int* __restrict__ d0, const int* __restrict__ d1,
    const int* __restrict__ d2, int b1, int b2, int* __restrict__ chunk_hist,
    int E, int NB, int CH) {
  __shared__ int hist[256];
  int t = threadIdx.x;
  for (int b = t; b < NB; b += 256) hist[b] = 0;
  __syncthreads();
  int cstart = blockIdx.x * CH;
  int cend = min(cstart + CH, 3 * E);
  for (int i = cstart + t; i < cend; i += 256) {
    int r = (i >= 2 * E) ? 2 : (i >= E) ? 1 : 0;
    int j = i - r * E;
    const int* dp = (r == 0) ? d0 : (r == 1) ? d1 : d2;
    int base = (r == 0) ? 0 : (r == 1) ? b1 : b2;
    int grow = dp[j] + base;
    atomicAdd(&hist[grow >> RPB_SHIFT], 1);
  }
  __syncthreads();
  for (int b = t; b < NB; b += 256) hist[b] = hist[b];  // no-op barrier aid
  for (int b = t; b < NB; b += 256) chunk_hist[b * NCH + blockIdx.x] = hist[b];
}

// per-bucket scan over its NCH chunk counts -> exclusive offsets + totals
__global__ __launch_bounds__(256) void bin_scan_kernel(
    int* __restrict__ chunk_hist, int* __restrict__ bucket_tot) {
  __shared__ int sh[256];
  int t = threadIdx.x;
  int x = chunk_hist[blockIdx.x * NCH + t];
  sh[t] = x;
  __syncthreads();
#pragma unroll
  for (int off = 1; off < 256; off <<= 1) {
    int v = (t >= off) ? sh[t - off] : 0;
    __syncthreads();
    sh[t] += v;
    __syncthreads();
  }
  chunk_hist[blockIdx.x * NCH + t] = sh[t] - x;  // exclusive within bucket
  if (t == 255) bucket_tot[blockIdx.x] = sh[t];
}

// single block: exclusive scan (n <= 1024) — used for bucket bases and
// (via 1024-chunk path) row_ptr chunk offsets.
__global__ __launch_bounds__(1024) void scan_tops_kernel(
    const int* __restrict__ vals, int* __restrict__ out, int n) {
  __shared__ int sh[1024];
  int t = threadIdx.x;
  int x = (t < n) ? vals[t] : 0;
  sh[t] = x;
  __syncthreads();
#pragma unroll
  for (int off = 1; off < 1024; off <<= 1) {
    int v = (t >= off) ? sh[t - off] : 0;
    __syncthreads();
    sh[t] += v;
    __syncthreads();
  }
  if (t < n) out[t] = sh[t] - x;  // exclusive
}

// replay chunk, claim slots via LDS cursors, write bucket-grouped pairs
__global__ __launch_bounds__(256) void bin_scatter_kernel(
    const int* __restrict__ s0, const int* __restrict__ d0,
    const int* __restrict__ s1, const int* __restrict__ d1,
    const int* __restrict__ s2, const int* __restrict__ d2, int b1, int b2,
    const int* __restrict__ chunk_hist, const int* __restrict__ bucket_base,
    int* __restrict__ bbs, int* __restrict__ bbg, int E, int NB, int CH) {
  __shared__ int cur[256];
  int t = threadIdx.x;
  for (int b = t; b < NB; b += 256)
    cur[b] = bucket_base[b] + chunk_hist[b * NCH + blockIdx.x];
  __syncthreads();
  int cstart = blockIdx.x * CH;
  int cend = min(cstart + CH, 3 * E);
  for (int i = cstart + t; i < cend; i += 256) {
    int r = (i >= 2 * E) ? 2 : (i >= E) ? 1 : 0;
    int j = i - r * E;
    const int* dp = (r == 0) ? d0 : (r == 1) ? d1 : d2;
    const int* sp = (r == 0) ? s0 : (r == 1) ? s1 : s2;
    int base = (r == 0) ? 0 : (r == 1) ? b1 : b2;
    int grow = dp[j] + base;
    int idx = atomicAdd(&cur[grow >> RPB_SHIFT], 1);
    bbs[idx] = sp[j];
    bbg[idx] = grow;
  }
}

// one block per bucket: LDS row histogram -> coalesced per-row counts
__global__ __launch_bounds__(256) void row_count_kernel(
    const int* __restrict__ bbg, const int* __restrict__ bucket_base,
    const int* __restrict__ bucket_tot, int* __restrict__ cnt, int NT) {
  __shared__ int c4[RPB];
  int t = threadIdx.x;
  int b = blockIdx.x;
  for (int r = t; r < RPB; r += 256) c4[r] = 0;
  __syncthreads();
  int ps = bucket_base[b], pe = ps + bucket_tot[b];
  int row0 = b << RPB_SHIFT;
  for (int i = ps + t; i < pe; i += 256) atomicAdd(&c4[bbg[i] - row0], 1);
  __syncthreads();
  for (int r = t; r < RPB; r += 256) {
    int row = row0 + r;
    if (row < NT) cnt[row] = c4[r];
  }
}

// per-1024-chunk inclusive scan of row counts; incl may alias counts
__global__ __launch_bounds__(1024) void scan_chunk_kernel(
    const int* __restrict__ counts, int* __restrict__ incl,
    int* __restrict__ chunk_tot, int N) {
  __shared__ int sh[1024];
  int t = threadIdx.x;
  int i = blockIdx.x * 1024 + t;
  int x = (i < N) ? counts[i] : 0;
  sh[t] = x;
  __syncthreads();
#pragma unroll
  for (int off = 1; off < 1024; off <<= 1) {
    int v = (t >= off) ? sh[t - off] : 0;
    __syncthreads();
    sh[t] += v;
    __syncthreads();
  }
  if (i < N) incl[i] = sh[t];
  if (t == 1023) chunk_tot[blockIdx.x] = sh[t];
}

__global__ __launch_bounds__(256) void finalize_ptr_kernel(
    const int* __restrict__ incl, const int* __restrict__ chunk_off,
    int* __restrict__ row_ptr, int N) {
  int i = blockIdx.x * 256 + threadIdx.x;
  if (i >= N) return;
  row_ptr[i + 1] = incl[i] + chunk_off[i >> 10];
  if (i == 0) row_ptr[0] = 0;
}

// one block per bucket: place pairs via LDS row-cursors into esrc
__global__ __launch_bounds__(256) void bucket_scatter_kernel(
    const int* __restrict__ bbs, const int* __restrict__ bbg,
    const int* __restrict__ bucket_base, const int* __restrict__ bucket_tot,
    const int* __restrict__ row_ptr, int* __restrict__ esrc, int NT) {
  __shared__ int cur4[RPB];
  int t = threadIdx.x;
  int b = blockIdx.x;
  int row0 = b << RPB_SHIFT;
  for (int r = t; r < RPB; r += 256) {
    int row = row0 + r;
    if (row < NT) cur4[r] = row_ptr[row];
  }
  __syncthreads();
  int ps = bucket_base[b], pe = ps + bucket_tot[b];
  for (int i = ps + t; i < pe; i += 256) {
    int lr = bbg[i] - row0;
    int pos = atomicAdd(&cur4[lr], 1);
    esrc[pos] = bbs[i];
  }
}

// ================= fused pull-based GATv2 row kernel =======================
// One wave per dst row; 4 groups of 16 lanes, each group owns edges
// j = jbeg+g, +4, ... with float4 channels per lane (4 gathers in flight).
// Per-group online softmax (m,z,acc); groups merged by xor-16/32 butterfly.
__global__ __launch_bounds__(256) void gat_row_kernel(
    const float* __restrict__ fs, const float* __restrict__ fd,
    const int* __restrict__ row_ptr, const int* __restrict__ esrc,
    const float* __restrict__ attn, const float* __restrict__ bias,
    const float* __restrict__ resid, float* __restrict__ out, int Nd) {
  const int lane = threadIdx.x & 63;
  const int d = (blockIdx.x * 256 + threadIdx.x) >> 6;
  if (d >= Nd) return;
  const int g = lane >> 4;        // group 0..3
  const int c = (lane & 15) * 4;  // channel base

  const float4 aw = *reinterpret_cast<const float4*>(&attn[c]);
  const float4 fdv = *reinterpret_cast<const float4*>(&fd[d * 64 + c]);
  const int jbeg = row_ptr[d];
  const int jend = row_ptr[d + 1];

  float m = -1e30f, z = 0.f;
  float4 acc = {0.f, 0.f, 0.f, 0.f};
  for (int j = jbeg + g; j < jend; j += 4) {
    int s = esrc[j];
    float4 fsv = *reinterpret_cast<const float4*>(&fs[s * 64 + c]);
    float vx = fsv.x + fdv.x; vx = (vx > 0.f) ? vx : 0.2f * vx;
    float vy = fsv.y + fdv.y; vy = (vy > 0.f) ? vy : 0.2f * vy;
    float vz = fsv.z + fdv.z; vz = (vz > 0.f) ? vz : 0.2f * vz;
    float vw = fsv.w + fdv.w; vw = (vw > 0.f) ? vw : 0.2f * vw;
    float p = vx * aw.x + vy * aw.y + vz * aw.z + vw * aw.w;
#pragma unroll
    for (int off = 1; off < 16; off <<= 1) p += __shfl_xor(p, off, 64);
    float mn = fmaxf(m, p);
    float sc = __expf(m - mn);  // first edge: exp(-1e30-p) -> 0
    float w = __expf(p - mn);
    z = z * sc + w;
    acc.x = acc.x * sc + w * fsv.x;
    acc.y = acc.y * sc + w * fsv.y;
    acc.z = acc.z * sc + w * fsv.z;
    acc.w = acc.w * sc + w * fsv.w;
    m = mn;
  }
  // merge the 4 groups (empty groups have m=-1e30, z=0 -> contribute 0)
#pragma unroll
  for (int off = 16; off < 64; off <<= 1) {
    float m_o = __shfl_xor(m, off, 64);
    float z_o = __shfl_xor(z, off, 64);
    float ax = __shfl_xor(acc.x, off, 64);
    float ay = __shfl_xor(acc.y, off, 64);
    float az = __shfl_xor(acc.z, off, 64);
    float aww = __shfl_xor(acc.w, off, 64);
    float mn = fmaxf(m, m_o);
    float s0 = __expf(m - mn), s1 = __expf(m_o - mn);
    z = z * s0 + z_o * s1;
    acc.x = acc.x * s0 + ax * s1;
    acc.y = acc.y * s0 + ay * s1;
    acc.z = acc.z * s0 + az * s1;
    acc.w = acc.w * s0 + aww * s1;
    m = mn;
  }
  if (g == 0) {
    float inv = (z > 0.f) ? 1.f / z : 0.f;
    float4 bb = *reinterpret_cast<const float4*>(&bias[c]);
    float4 o;
    o.x = acc.x * inv + bb.x;
    o.y = acc.y * inv + bb.y;
    o.z = acc.z * inv + bb.z;
    o.w = acc.w * inv + bb.w;
    if (resid) {
      float4 rr = *reinterpret_cast<const float4*>(&resid[d * 64 + c]);
      o.x += rr.x; o.y += rr.y; o.z += rr.z; o.w += rr.w;
    }
    *reinterpret_cast<float4*>(&out[d * 64 + c]) = o;
  }
}

// ---- collapse Linear(128,128)->Linear(128,1) into one 128-vector ----------
// wbuf layout: [0..127]=w_inf, [128]=c_inf, [130..257]=w_int, [258]=c_int
__global__ __launch_bounds__(256) void weff_kernel(
    const float* __restrict__ W1i, const float* __restrict__ b1i,
    const float* __restrict__ W2i, const float* __restrict__ b2i,
    const float* __restrict__ W1t, const float* __restrict__ b1t,
    const float* __restrict__ W2t, const float* __restrict__ b2t,
    float* __restrict__ wbuf) {
  int t = threadIdx.x;
  const float* W1 = (t < 128) ? W1i : W1t;
  const float* W2 = (t < 128) ? W2i : W2t;
  int i = t & 127;
  int base = (t < 128) ? 0 : 130;
  float s = 0.f;
  for (int j = 0; j < 128; ++j) s += W1[i * 128 + j] * W2[j];
  wbuf[base + i] = s;
  if (i == 0) {
    const float* b1 = (t < 128) ? b1i : b1t;
    const float* b2 = (t < 128) ? b2i : b2t;
    float c = b2[0];
    for (int j = 0; j < 128; ++j) c += b1[j] * W2[j];
    wbuf[base + 128] = c;
  }
}

// ---- h_inf/h_int per user + per-block BN partial sums (NO atomics) --------
__global__ __launch_bounds__(256) void fuse_h_kernel(
    const float* __restrict__ ue, const float* __restrict__ p,
    const float* __restrict__ q, const float* __restrict__ wbuf,
    float* __restrict__ h_inf, float* __restrict__ h_int,
    double* __restrict__ partials, int NU) {
  const int lane = threadIdx.x & 63;
  const int wv = threadIdx.x >> 6;
  const int wave = blockIdx.x * 4 + wv;
  const int nwaves = gridDim.x * 4;

  const float wi_u = wbuf[lane];
  const float wi_p = wbuf[64 + lane];
  const float wt_u = wbuf[130 + lane];
  const float wt_q = wbuf[194 + lane];
  const float ci = wbuf[128];
  const float ct = wbuf[258];

  double s0 = 0., s1 = 0., s2 = 0., s3 = 0.;
  for (int u = wave; u < NU; u += nwaves) {
    float uv = ue[u * 64 + lane];
    float hi = uv * wi_u + p[u * 64 + lane] * wi_p;
    float ht = uv * wt_u + q[u * 64 + lane] * wt_q;
    hi = waveReduceSum(hi) + ci;
    ht = waveReduceSum(ht) + ct;
    if (lane == 0) {
      h_inf[u] = hi;
      h_int[u] = ht;
    }
    s0 += (double)hi;
    s1 += (double)hi * (double)hi;
    s2 += (double)ht;
    s3 += (double)ht * (double)ht;
  }

  __shared__ double sh[4][4];
  if (lane == 0) {
    sh[wv][0] = s0;
    sh[wv][1] = s1;
    sh[wv][2] = s2;
    sh[wv][3] = s3;
  }
  __syncthreads();
  if (threadIdx.x < 4) {
    int k = threadIdx.x;
    partials[blockIdx.x * 4 + k] = sh[0][k] + sh[1][k] + sh[2][k] + sh[3][k];
  }
}

__global__ __launch_bounds__(256) void reduce_stats_kernel(
    const double* __restrict__ partials, double* __restrict__ stats,
    int nblocks) {
  int k = threadIdx.x & 3;
  int bstart = threadIdx.x >> 2;  // 0..63
  double s = 0.;
  for (int b = bstart; b < nblocks; b += 64) s += partials[b * 4 + k];
  __shared__ double sh[256];
  sh[threadIdx.x] = s;
  __syncthreads();
  if (threadIdx.x < 4) {
    double acc = 0.;
    for (int i = 0; i < 64; ++i) acc += sh[i * 4 + threadIdx.x];
    stats[threadIdx.x] = acc;
  }
}

// ---- final: BN + leaky + 2-way softmax + gated sum + residual -------------
__global__ __launch_bounds__(256) void fuse_out_kernel(
    const float* __restrict__ ue, const float* __restrict__ p,
    const float* __restrict__ q, const float* __restrict__ h_inf,
    const float* __restrict__ h_int, const double* __restrict__ stats,
    const float* __restrict__ gi, const float* __restrict__ bei,
    const float* __restrict__ gt, const float* __restrict__ bet,
    float* __restrict__ out, int NU) {
  int i = blockIdx.x * 256 + threadIdx.x;
  if (i >= NU * 64) return;
  int u = i >> 6;
  double invN = 1.0 / (double)NU;
  float mu_i = (float)(stats[0] * invN);
  float var_i = (float)(stats[1] * invN) - mu_i * mu_i;
  float mu_t = (float)(stats[2] * invN);
  float var_t = (float)(stats[3] * invN) - mu_t * mu_t;
  float si = gi[0] * (h_inf[u] - mu_i) / sqrtf(var_i + 1e-5f) + bei[0];
  si = (si > 0.f) ? si : 0.01f * si;
  float st = gt[0] * (h_int[u] - mu_t) / sqrtf(var_t + 1e-5f) + bet[0];
  st = (st > 0.f) ? st : 0.01f * st;
  float mx = fmaxf(si, st);
  float e0 = expf(si - mx), e1 = expf(st - mx);
  float inv = 1.f / (e0 + e1);
  out[i] = (e0 * inv) * p[i] + (e1 * inv) * q[i] + ue[i];
}

// ---------------------------------------------------------------------------
extern "C" void kernel_launch(void* const* d_in, const int* in_sizes, int n_in,
                              void* d_out, int out_size, void* d_ws,
                              size_t ws_size, hipStream_t stream) {
  const float* user_emb = (const float*)d_in[0];
  const float* item_emb = (const float*)d_in[1];
  const int* rate_src = (const int*)d_in[2];
  const int* rate_dst = (const int*)d_in[3];
  const int* rb_src = (const int*)d_in[4];
  const int* rb_dst = (const int*)d_in[5];
  const int* tr_src = (const int*)d_in[6];
  const int* tr_dst = (const int*)d_in[7];
  const float* rate_Wsrc = (const float*)d_in[8];
  const float* rate_bsrc = (const float*)d_in[9];
  const float* rate_Wdst = (const float*)d_in[10];
  const float* rate_bdst = (const float*)d_in[11];
  const float* rate_attn = (const float*)d_in[12];
  const float* rate_bias = (const float*)d_in[13];
  const float* rb_Wsrc = (const float*)d_in[14];
  const float* rb_bsrc = (const float*)d_in[15];
  const float* rb_Wdst = (const float*)d_in[16];
  const float* rb_bdst = (const float*)d_in[17];
  const float* rb_attn = (const float*)d_in[18];
  const float* rb_bias = (const float*)d_in[19];
  const float* tr_Wsrc = (const float*)d_in[20];
  const float* tr_bsrc = (const float*)d_in[21];
  const float* tr_Wdst = (const float*)d_in[22];
  const float* tr_bdst = (const float*)d_in[23];
  const float* tr_attn = (const float*)d_in[24];
  const float* tr_bias = (const float*)d_in[25];
  const float* inf_W1 = (const float*)d_in[26];
  const float* inf_b1 = (const float*)d_in[27];
  const float* inf_W2 = (const float*)d_in[28];
  const float* inf_b2 = (const float*)d_in[29];
  const float* inf_g = (const float*)d_in[30];
  const float* inf_be = (const float*)d_in[31];
  const float* int_W1 = (const float*)d_in[32];
  const float* int_b1 = (const float*)d_in[33];
  const float* int_W2 = (const float*)d_in[34];
  const float* int_b2 = (const float*)d_in[35];
  const float* int_g = (const float*)d_in[36];
  const float* int_be = (const float*)d_in[37];

  const int NU = in_sizes[0] / 64;
  const int NI = in_sizes[1] / 64;
  const int E = in_sizes[2];
  const size_t MX = (size_t)((NU > NI) ? NU : NI);
  const int NT = 2 * NU + NI;             // concatenated row space
  const int NB = (NT + RPB - 1) >> RPB_SHIFT;  // buckets (must be <= 256)
  const int CH = (3 * E + NCH - 1) / NCH;      // edges per chunk

  // workspace carve-up (256B aligned)
  char* ws = (char*)d_ws;
  size_t off = 0;
  auto alloc = [&](size_t bytes) -> void* {
    void* pp = ws + off;
    off += (bytes + 255) & ~(size_t)255;
    return pp;
  };
  float* fs = (float*)alloc(MX * 64 * 4);
  float* fd = (float*)alloc(MX * 64 * 4);
  float* q_acc = (float*)alloc((size_t)NU * 64 * 4);
  int* cnt = (int*)alloc((size_t)NT * 4);  // row counts -> incl scan
  int* row_ptr = (int*)alloc(((size_t)NT + 1) * 4);
  int* esrc = (int*)alloc((size_t)3 * E * 4);
  int* chunk_hist = (int*)alloc((size_t)256 * NCH * 4);
  int* bucket_tot = (int*)alloc(1024 * 4);
  int* bucket_base = (int*)alloc(1024 * 4);
  int* chunk_tot = (int*)alloc(1024 * 4);
  int* chunk_off = (int*)alloc(1024 * 4);
  float* h_inf = (float*)alloc((size_t)NU * 4);
  float* h_int = (float*)alloc((size_t)NU * 4);
  float* wbuf = (float*)alloc(272 * 4);
  double* stats = (double*)alloc(4 * 8);
  double* partials = (double*)alloc((size_t)FH_BLOCKS * 4 * 8);

  // pair buffers alias fs/fd (only live during CSR build, before proj64)
  int* bbs = (int*)fs;  // 3E ints = 12 MB <= MX*64*4
  int* bbg = (int*)fd;

  float* p_acc = (float*)d_out;                       // user region of output
  float* item_acc = (float*)d_out + (size_t)NU * 64;  // item region

  auto projGrid = [](int n) { return (n + 63) / 64; };
  auto elemGrid = [](int total) { return (total + 255) / 256; };

  weff_kernel<<<1, 256, 0, stream>>>(inf_W1, inf_b1, inf_W2, inf_b2, int_W1,
                                     int_b1, int_W2, int_b2, wbuf);

  // ---- binned CSR build over all 3 relations ----
  bin_count_kernel<<<NCH, 256, 0, stream>>>(tr_dst, rb_dst, rate_dst, NU,
                                            2 * NU, chunk_hist, E, NB, CH);
  bin_scan_kernel<<<NB, 256, 0, stream>>>(chunk_hist, bucket_tot);
  scan_tops_kernel<<<1, 1024, 0, stream>>>(bucket_tot, bucket_base, NB);
  bin_scatter_kernel<<<NCH, 256, 0, stream>>>(
      tr_src, tr_dst, rb_src, rb_dst, rate_src, rate_dst, NU, 2 * NU,
      chunk_hist, bucket_base, bbs, bbg, E, NB, CH);
  row_count_kernel<<<NB, 256, 0, stream>>>(bbg, bucket_base, bucket_tot, cnt,
                                           NT);
  int nchunks = (NT + 1023) / 1024;
  scan_chunk_kernel<<<nchunks, 1024, 0, stream>>>(cnt, cnt, chunk_tot, NT);
  scan_tops_kernel<<<1, 1024, 0, stream>>>(chunk_tot, chunk_off, nchunks);
  finalize_ptr_kernel<<<elemGrid(NT), 256, 0, stream>>>(cnt, chunk_off,
                                                        row_ptr, NT);
  bucket_scatter_kernel<<<NB, 256, 0, stream>>>(bbs, bbg, bucket_base,
                                                bucket_tot, row_ptr, esrc, NT);

  // ---- trust: user -> user  => p_hair (d_out user region) ----
  proj64_kernel<<<projGrid(NU), 256, 0, stream>>>(user_emb, tr_Wsrc, tr_bsrc,
                                                  fs, NU);
  proj64_kernel<<<projGrid(NU), 256, 0, stream>>>(user_emb, tr_Wdst, tr_bdst,
                                                  fd, NU);
  gat_row_kernel<<<(NU + 3) / 4, 256, 0, stream>>>(
      fs, fd, row_ptr, esrc, tr_attn, tr_bias, nullptr, p_acc, NU);

  // ---- ratedby: item -> user  => q_hair ----
  proj64_kernel<<<projGrid(NI), 256, 0, stream>>>(item_emb, rb_Wsrc, rb_bsrc,
                                                  fs, NI);
  proj64_kernel<<<projGrid(NU), 256, 0, stream>>>(user_emb, rb_Wdst, rb_bdst,
                                                  fd, NU);
  gat_row_kernel<<<(NU + 3) / 4, 256, 0, stream>>>(
      fs, fd, row_ptr + NU, esrc, rb_attn, rb_bias, nullptr, q_acc, NU);

  // ---- rate: user -> item  => item_out (d_out item region, +resid) ----
  proj64_kernel<<<projGrid(NU), 256, 0, stream>>>(user_emb, rate_Wsrc,
                                                  rate_bsrc, fs, NU);
  proj64_kernel<<<projGrid(NI), 256, 0, stream>>>(item_emb, rate_Wdst,
                                                  rate_bdst, fd, NI);
  gat_row_kernel<<<(NI + 3) / 4, 256, 0, stream>>>(
      fs, fd, row_ptr + 2 * NU, esrc, rate_attn, rate_bias, item_emb,
      item_acc, NI);

  // ---- fusion ----
  fuse_h_kernel<<<FH_BLOCKS, 256, 0, stream>>>(user_emb, p_acc, q_acc, wbuf,
                                               h_inf, h_int, partials, NU);
  reduce_stats_kernel<<<1, 256, 0, stream>>>(partials, stats, FH_BLOCKS);
  fuse_out_kernel<<<elemGrid(NU * 64), 256, 0, stream>>>(
      user_emb, p_acc, q_acc, h_inf, h_int, stats, inf_g, inf_be, int_g,
      int_be, (float*)d_out, NU);
}